// Round 6
// baseline (211985.889 us; speedup 1.0000x reference)
//
#include <hip/hip_runtime.h>
#include <hip/hip_bf16.h>
#include <hip/hip_fp16.h>

// ---------------------------------------------------------------------------
// LuxrNet: conv->conv->FFN (parallel branch) + 2-layer GRU over a 32768-step
// flattened scan (serial branch) + joiner + output head.
// Round 5/6: BOTH GRU layers fused into one kernel (768 threads, 12 waves),
// pipelined one step apart. L0 = 256-thread pair-split (as before); L1 = 512
// threads, quad-split over concat K=256 ([wih1*h1 | whh1*h2]), n-gate parts
// kept separate via shfl_xor(2) exchange. One barrier per step, no global
// h1 traffic, no gi1 GEMM.
// ---------------------------------------------------------------------------

typedef _Float16 h2_t __attribute__((ext_vector_type(2)));

#if defined(__has_builtin)
#if __has_builtin(__builtin_amdgcn_fdot2)
#define HAVE_FDOT2 1
#endif
#endif

__device__ __forceinline__ h2_t f2h2bits(float x) {
  union { float f; h2_t h; } u; u.f = x; return u.h;
}

__device__ __forceinline__ float fdot2(h2_t a, h2_t b, float c) {
#ifdef HAVE_FDOT2
  return __builtin_amdgcn_fdot2(a, b, c, false);
#else
  return c + (float)a.x * (float)b.x + (float)a.y * (float)b.y;
#endif
}

__device__ __forceinline__ float sigmoidf_(float x) {
  return 1.f / (1.f + __expf(-x));
}
__device__ __forceinline__ float tanhf_(float x) {
  return 2.f / (1.f + __expf(-2.f * x)) - 1.f;
}

// ---------------------------------------------------------------------------
// conv1: in (512,10,30,30), w (64,10,8,8), stride 2 -> out (512,64,12,12), relu
// ---------------------------------------------------------------------------
__global__ __launch_bounds__(256) void conv1_k(
    const float* __restrict__ in, const float* __restrict__ w,
    const float* __restrict__ bias, float* __restrict__ out) {
  int idx = blockIdx.x * 256 + threadIdx.x;     // 512*64*144 total, exact
  int pos = idx % 144;
  int co  = (idx / 144) & 63;
  int b   = idx / (144 * 64);
  int oh = pos / 12, ow = pos % 12;
  const float* ip = in + (size_t)b * 9000 + (oh * 2) * 30 + ow * 2;
  const float* wp = w + co * 640;
  float acc = bias[co];
  for (int ci = 0; ci < 10; ci++) {
#pragma unroll
    for (int kh = 0; kh < 8; kh++) {
      const float* r  = ip + ci * 900 + kh * 30;
      const float* wr = wp + ci * 64 + kh * 8;
#pragma unroll
      for (int kw = 0; kw < 8; kw++) acc += r[kw] * wr[kw];
    }
  }
  out[idx] = fmaxf(acc, 0.f);
}

// ---------------------------------------------------------------------------
// conv2: in (512,64,12,12), w (128,64,4,4), stride 2 -> out (512,128,5,5), relu
// ---------------------------------------------------------------------------
__global__ __launch_bounds__(256) void conv2_k(
    const float* __restrict__ in, const float* __restrict__ w,
    const float* __restrict__ bias, float* __restrict__ out) {
  int idx = blockIdx.x * 256 + threadIdx.x;     // 512*128*25 total, exact
  int pos = idx % 25;
  int co  = (idx / 25) & 127;
  int b   = idx / 3200;
  int oh = pos / 5, ow = pos % 5;
  const float* ip = in + (size_t)b * 9216 + (oh * 2) * 12 + ow * 2;
  const float* wp = w + co * 1024;
  float acc = bias[co];
  for (int ci = 0; ci < 64; ci++) {
#pragma unroll
    for (int kh = 0; kh < 4; kh++) {
      const float* r  = ip + ci * 144 + kh * 12;
      const float* wr = wp + ci * 16 + kh * 4;
#pragma unroll
      for (int kw = 0; kw < 4; kw++) acc += r[kw] * wr[kw];
    }
  }
  out[idx] = fmaxf(acc, 0.f);
}

// ---------------------------------------------------------------------------
// Generic fp32 GEMM: C[m*ldc+n] = bias[n] + sum_k X[m*K+k] * W[n*K+k]
// Requires M%64==0, N%64==0, K%16==0. 64x64 tile, 256 threads, 4x4 micro.
// ---------------------------------------------------------------------------
__global__ __launch_bounds__(256) void gemm_xwt(
    const float* __restrict__ X, const float* __restrict__ W,
    const float* __restrict__ bias, float* __restrict__ C,
    int M, int N, int K, int ldc, int relu) {
  __shared__ float Xs[16][68];
  __shared__ float Ws[16][68];
  int tid = threadIdx.x;
  int m0 = blockIdx.y * 64, n0 = blockIdx.x * 64;
  int lr = tid >> 2;            // 0..63
  int lc = (tid & 3) << 2;      // 0,4,8,12
  int tm = tid >> 4, tn = tid & 15;
  float acc[4][4] = {};
  for (int k0 = 0; k0 < K; k0 += 16) {
    const float4 xv = *(const float4*)(X + (size_t)(m0 + lr) * K + k0 + lc);
    const float4 wv = *(const float4*)(W + (size_t)(n0 + lr) * K + k0 + lc);
    Xs[lc + 0][lr] = xv.x; Xs[lc + 1][lr] = xv.y;
    Xs[lc + 2][lr] = xv.z; Xs[lc + 3][lr] = xv.w;
    Ws[lc + 0][lr] = wv.x; Ws[lc + 1][lr] = wv.y;
    Ws[lc + 2][lr] = wv.z; Ws[lc + 3][lr] = wv.w;
    __syncthreads();
#pragma unroll
    for (int kk = 0; kk < 16; kk++) {
      float a[4], bb[4];
#pragma unroll
      for (int i = 0; i < 4; i++) a[i] = Xs[kk][tm * 4 + i];
#pragma unroll
      for (int j = 0; j < 4; j++) bb[j] = Ws[kk][tn * 4 + j];
#pragma unroll
      for (int i = 0; i < 4; i++)
#pragma unroll
        for (int j = 0; j < 4; j++) acc[i][j] += a[i] * bb[j];
    }
    __syncthreads();
  }
#pragma unroll
  for (int i = 0; i < 4; i++) {
    int m = m0 + tm * 4 + i;
#pragma unroll
    for (int j = 0; j < 4; j++) {
      int n = n0 + tn * 4 + j;
      float v = acc[i][j] + bias[n];
      if (relu) v = fmaxf(v, 0.f);
      C[(size_t)m * ldc + n] = v;
    }
  }
}

// ---------------------------------------------------------------------------
// gi0 = seq @ wih0^T + bih0 where seq[s] = uf[s&511, s>>9, :]  (K=8).
// ---------------------------------------------------------------------------
__global__ __launch_bounds__(384) void gi0_k(
    const float* __restrict__ uf,   // (512,64,8)
    const float* __restrict__ wih,  // (384,8)
    const float* __restrict__ bih,  // (384)
    float* __restrict__ gi) {       // (32768,384)
  int n = threadIdx.x;
  int s0 = blockIdx.x * 32;
  __shared__ float xs[32][8];
  if (n < 256) {
    int ss = s0 + (n >> 3);
    int k = n & 7;
    xs[n >> 3][k] = uf[(size_t)(ss & 511) * 512 + (ss >> 9) * 8 + k];
  }
  float w[8];
#pragma unroll
  for (int k = 0; k < 8; k++) w[k] = wih[n * 8 + k];
  float b = bih[n];
  __syncthreads();
#pragma unroll 4
  for (int i = 0; i < 32; i++) {
    float a = b;
#pragma unroll
    for (int k = 0; k < 8; k++) a += w[k] * xs[i][k];
    gi[(size_t)(s0 + i) * 384 + n] = a;
  }
}

// ---------------------------------------------------------------------------
// Fused 2-layer GRU scan. One WG, 768 threads (12 waves), pipelined:
// at outer step s, L0 group (t<256) computes h1[s], L1 group computes h2[s-1].
// h1/h2 ping-pong in LDS (f16); ONE barrier per step (lgkmcnt-only).
// L0: pair-split K=128, 96 fdot2/thread, shfl_xor(1) reduce, gates redundant.
// L1: quad-split over concat K=256: lanes c=0,1 -> wih1*h1 halves,
//     c=2,3 -> whh1*h2 halves. shfl_xor(1) sums within source, shfl_xor(2)
//     EXCHANGES (not sums) so i_n and h_n stay separate for n-gate.
// Global traffic: gi0 prefetch reads + 512 tail jx writes only.
// ---------------------------------------------------------------------------
#define L0_STEP(HIN, HOUT, G0, G1, G2)                                        \
  {                                                                           \
    const float4* hp4 = (const float4*)(&HIN[half * 64]);                     \
    float ar = br, az = bz, an = bn;                                          \
    _Pragma("unroll")                                                         \
    for (int q = 0; q < 8; q++) {                                             \
      float4 blk = hp4[q];                                                    \
      h2_t x0 = f2h2bits(blk.x), x1 = f2h2bits(blk.y);                        \
      h2_t x2 = f2h2bits(blk.z), x3 = f2h2bits(blk.w);                        \
      ar = fdot2(wr[4*q+0], x0, ar); az = fdot2(wz[4*q+0], x0, az);           \
      an = fdot2(wn[4*q+0], x0, an);                                          \
      ar = fdot2(wr[4*q+1], x1, ar); az = fdot2(wz[4*q+1], x1, az);           \
      an = fdot2(wn[4*q+1], x1, an);                                          \
      ar = fdot2(wr[4*q+2], x2, ar); az = fdot2(wz[4*q+2], x2, az);           \
      an = fdot2(wn[4*q+2], x2, an);                                          \
      ar = fdot2(wr[4*q+3], x3, ar); az = fdot2(wz[4*q+3], x3, az);           \
      an = fdot2(wn[4*q+3], x3, an);                                          \
    }                                                                         \
    ar += __shfl_xor(ar, 1); az += __shfl_xor(az, 1); an += __shfl_xor(an, 1);\
    float r = sigmoidf_((G0) + ar);                                           \
    float z = sigmoidf_((G1) + az);                                           \
    float n = tanhf_((G2) + r * an);                                          \
    float hn = (1.f - z) * n + z * hreg;                                      \
    hreg = hn;                                                                \
    HOUT[o] = (_Float16)hn;                                                   \
  }

#define L1_STEP(H1R, H2R, H2W, SIDX)                                          \
  {                                                                           \
    const float4* xp4 = (c < 2)                                               \
        ? (const float4*)(&H1R[(c & 1) * 64])                                 \
        : (const float4*)(&H2R[(c & 1) * 64]);                                \
    float ar = e0, az = e1, an = e2;                                          \
    _Pragma("unroll")                                                         \
    for (int q = 0; q < 8; q++) {                                             \
      float4 blk = xp4[q];                                                    \
      h2_t x0 = f2h2bits(blk.x), x1 = f2h2bits(blk.y);                        \
      h2_t x2 = f2h2bits(blk.z), x3 = f2h2bits(blk.w);                        \
      ar = fdot2(vr[4*q+0], x0, ar); az = fdot2(vz[4*q+0], x0, az);           \
      an = fdot2(vn[4*q+0], x0, an);                                          \
      ar = fdot2(vr[4*q+1], x1, ar); az = fdot2(vz[4*q+1], x1, az);           \
      an = fdot2(vn[4*q+1], x1, an);                                          \
      ar = fdot2(vr[4*q+2], x2, ar); az = fdot2(vz[4*q+2], x2, az);           \
      an = fdot2(vn[4*q+2], x2, an);                                          \
      ar = fdot2(vr[4*q+3], x3, ar); az = fdot2(vz[4*q+3], x3, az);           \
      an = fdot2(vn[4*q+3], x3, an);                                          \
    }                                                                         \
    ar += __shfl_xor(ar, 1); az += __shfl_xor(az, 1); an += __shfl_xor(an, 1);\
    float or_ = __shfl_xor(ar, 2), oz = __shfl_xor(az, 2),                    \
          on = __shfl_xor(an, 2);                                             \
    float pre_r = ar + or_, pre_z = az + oz;                                  \
    float i_n = (c < 2) ? an : on;                                            \
    float h_n = (c < 2) ? on : an;                                            \
    float r = sigmoidf_(pre_r);                                               \
    float z = sigmoidf_(pre_z);                                               \
    float n = tanhf_(i_n + r * h_n);                                          \
    float hn = (1.f - z) * n + z * hreg2;                                     \
    hreg2 = hn;                                                               \
    if (c == 0) {                                                             \
      H2W[o1] = (_Float16)hn;                                                 \
      if ((SIDX) >= S - 511)                                                  \
        jx[(size_t)((SIDX) - 1 - (S - 512)) * 640 + 512 + o1] = hn;           \
    }                                                                         \
  }

#define GRU_RELOAD(G0, G1, G2)                                                \
  { G0 = gp[0]; G1 = gp[128]; G2 = gp[256]; gp += 384; }

#define GRU_BARRIER()                                                         \
  __builtin_amdgcn_sched_barrier(0);                                          \
  asm volatile("s_waitcnt lgkmcnt(0)" ::: "memory");                          \
  __builtin_amdgcn_s_barrier();                                               \
  __builtin_amdgcn_sched_barrier(0);

#define FUSED_SLOT(H1R, H1W, H2R, H2W, G0, G1, G2, SIDX)                      \
  if (isL0) {                                                                 \
    if ((SIDX) < S) { L0_STEP(H1R, H1W, G0, G1, G2); }                        \
    GRU_RELOAD(G0, G1, G2);                                                   \
  } else {                                                                    \
    if ((SIDX) >= 1 && (SIDX) <= S) { L1_STEP(H1R, H2R, H2W, SIDX); }         \
  }                                                                           \
  GRU_BARRIER();

__global__ __launch_bounds__(768, 1) void fused_scan(
    const float* __restrict__ gi0,   // (S,384), includes bih0
    const float* __restrict__ whh0,  // (384,128)
    const float* __restrict__ bhh0,  // (384)
    const float* __restrict__ wih1,  // (384,128)
    const float* __restrict__ whh1,  // (384,128)
    const float* __restrict__ bih1,  // (384)
    const float* __restrict__ bhh1,  // (384)
    float* __restrict__ jx) {        // (512,640), cols 512..639
  const int S = 32768;
  const int t = threadIdx.x;
  const bool isL0 = (t < 256);

  alignas(16) __shared__ _Float16 h1a[128], h1b[128], h2a[128], h2b[128];

  // ---- L0 thread state (t < 256): o = t>>1, half = t&1 ----
  const int o = (t < 256) ? (t >> 1) : 0;
  const int half = t & 1;
  h2_t wr[32], wz[32], wn[32];
  float br = 0.f, bz = 0.f, bn = 0.f;
  float hreg = 0.f;

  // ---- L1 thread state (t >= 256): o1 = u>>2, c = u&3 ----
  const int u = t - 256;
  const int o1 = (t >= 256) ? (u >> 2) : 0;
  const int c = u & 3;
  h2_t vr[32], vz[32], vn[32];
  float e0 = 0.f, e1 = 0.f, e2 = 0.f;
  float hreg2 = 0.f;

  if (isL0) {
    const float2* pr = (const float2*)(whh0 + (size_t)(o)       * 128 + half * 64);
    const float2* pz = (const float2*)(whh0 + (size_t)(128 + o) * 128 + half * 64);
    const float2* pn = (const float2*)(whh0 + (size_t)(256 + o) * 128 + half * 64);
#pragma unroll
    for (int k = 0; k < 32; k++) {
      float2 a = pr[k], b = pz[k], d = pn[k];
      h2_t va; va.x = (_Float16)a.x; va.y = (_Float16)a.y; wr[k] = va;
      h2_t vb; vb.x = (_Float16)b.x; vb.y = (_Float16)b.y; wz[k] = vb;
      h2_t vc; vc.x = (_Float16)d.x; vc.y = (_Float16)d.y; wn[k] = vc;
    }
    br = half ? 0.f : bhh0[o];
    bz = half ? 0.f : bhh0[128 + o];
    bn = half ? 0.f : bhh0[256 + o];
  } else {
    // lanes c=0,1: wih1 halves (i_*); lanes c=2,3: whh1 halves (h_*)
    const float* M = (c < 2) ? wih1 : whh1;
    const float2* pr = (const float2*)(M + (size_t)(o1)       * 128 + (c & 1) * 64);
    const float2* pz = (const float2*)(M + (size_t)(128 + o1) * 128 + (c & 1) * 64);
    const float2* pn = (const float2*)(M + (size_t)(256 + o1) * 128 + (c & 1) * 64);
#pragma unroll
    for (int k = 0; k < 32; k++) {
      float2 a = pr[k], b = pz[k], d = pn[k];
      h2_t va; va.x = (_Float16)a.x; va.y = (_Float16)a.y; vr[k] = va;
      h2_t vb; vb.x = (_Float16)b.x; vb.y = (_Float16)b.y; vz[k] = vb;
      h2_t vc; vc.x = (_Float16)d.x; vc.y = (_Float16)d.y; vn[k] = vc;
    }
    if (c == 0) { e0 = bih1[o1]; e1 = bih1[128 + o1]; e2 = bih1[256 + o1]; }
    if (c == 2) { e0 = bhh1[o1]; e1 = bhh1[128 + o1]; e2 = bhh1[256 + o1]; }
  }

  if (t < 128) {
    h1a[t] = (_Float16)0.f;
    h2a[t] = (_Float16)0.f;
    h2b[t] = (_Float16)0.f;
  }

  // depth-4 register prefetch of gi0 rows (L0 threads only)
  const float* gp = gi0 + o;
  float gA0 = 0, gA1 = 0, gA2 = 0, gB0 = 0, gB1 = 0, gB2 = 0;
  float gC0 = 0, gC1 = 0, gC2 = 0, gD0 = 0, gD1 = 0, gD2 = 0;
  if (isL0) {
    GRU_RELOAD(gA0, gA1, gA2);
    GRU_RELOAD(gB0, gB1, gB2);
    GRU_RELOAD(gC0, gC1, gC2);
    GRU_RELOAD(gD0, gD1, gD2);
  }
  __syncthreads();

  // 32772 steps (last 3 are no-ops); L0 active s<S, L1 active 1<=s<=S.
  // Prefetch reads up to gi0 row ~32775: lands in the jx region of d_ws
  // (in-bounds, barrier-ordered after the jx tail writes, values unused).
  for (int s = 0; s < 32772; s += 4) {
    FUSED_SLOT(h1a, h1b, h2a, h2b, gA0, gA1, gA2, s);
    FUSED_SLOT(h1b, h1a, h2b, h2a, gB0, gB1, gB2, s + 1);
    FUSED_SLOT(h1a, h1b, h2a, h2b, gC0, gC1, gC2, s + 2);
    FUSED_SLOT(h1b, h1a, h2b, h2a, gD0, gD1, gD2, s + 3);
  }
}

// ---------------------------------------------------------------------------
// out head: out[b,:] = hidden[b,:] @ out_w.T + out_b (relu pre-applied)
// ---------------------------------------------------------------------------
__global__ __launch_bounds__(64) void out_k(
    const float* __restrict__ hidden, const float* __restrict__ ow,
    const float* __restrict__ ob, float* __restrict__ out) {
  __shared__ float hrow[512];
  int b = blockIdx.x, t = threadIdx.x;
  float4* h4 = (float4*)hrow;
  const float4* src = (const float4*)(hidden + (size_t)b * 512);
  h4[t] = src[t];
  h4[t + 64] = src[t + 64];
  __syncthreads();
  if (t < 12) {
    float acc = ob[t];
    const float* wr = ow + t * 512;
    for (int k = 0; k < 512; k++) acc += hrow[k] * wr[k];
    out[(size_t)b * 12 + t] = acc;
  }
}

// ---------------------------------------------------------------------------
extern "C" void kernel_launch(void* const* d_in, const int* in_sizes, int n_in,
                              void* d_out, int out_size, void* d_ws,
                              size_t ws_size, hipStream_t stream) {
  const float* gf    = (const float*)d_in[0];   // (512,10,30,30)
  const float* uf    = (const float*)d_in[1];   // (512,64,8)
  const float* c1w   = (const float*)d_in[2];
  const float* c1b   = (const float*)d_in[3];
  const float* c2w   = (const float*)d_in[4];
  const float* c2b   = (const float*)d_in[5];
  const float* ffw   = (const float*)d_in[6];
  const float* ffb   = (const float*)d_in[7];
  const float* wih0  = (const float*)d_in[8];
  const float* whh0  = (const float*)d_in[9];
  const float* bih0  = (const float*)d_in[10];
  const float* bhh0  = (const float*)d_in[11];
  const float* wih1  = (const float*)d_in[12];
  const float* whh1  = (const float*)d_in[13];
  const float* bih1  = (const float*)d_in[14];
  const float* bhh1  = (const float*)d_in[15];
  const float* jw    = (const float*)d_in[16];
  const float* jb    = (const float*)d_in[17];
  const float* ow    = (const float*)d_in[18];
  const float* ob    = (const float*)d_in[19];
  float* outp = (float*)d_out;                  // (512,12)

  // workspace layout (floats). gi time-shares with conv scratch (conv1o/
  // conv2o dead before gi0 is written).
  float* ws     = (float*)d_ws;
  float* gi     = ws;                 // 32768*384 = 12,582,912 f
  float* conv1o = ws;                 //  4,718,592 f (aliases gi, earlier)
  float* conv2o = ws + 4718592;       //  1,638,400 f (aliases gi, earlier)
  float* jx     = ws + 12582912;      //  512*640 = 327,680 f
  float* hidden = jx + 327680;        //  512*512 = 262,144 f
  // total: ~13.17M floats = ~52.7 MB

  conv1_k<<<18432, 256, 0, stream>>>(gf, c1w, c1b, conv1o);
  conv2_k<<<6400, 256, 0, stream>>>(conv1o, c2w, c2b, conv2o);
  // glob = conv2o(512,3200) @ ffw.T + ffb -> jx cols [0,512)
  gemm_xwt<<<dim3(8, 8), 256, 0, stream>>>(conv2o, ffw, ffb, jx,
                                           512, 512, 3200, 640, 0);
  // gi0 = seq @ wih0^T + bih0  (overwrites conv scratch, now dead)
  gi0_k<<<1024, 384, 0, stream>>>(uf, wih0, bih0, gi);
  // fused 2-layer GRU scan; writes last 512 h2 rows into jx cols [512,640)
  fused_scan<<<1, 768, 0, stream>>>(gi, whh0, bhh0, wih1, whh1, bih1, bhh1,
                                    jx);
  // hidden = relu(jx(512,640) @ jw.T + jb)
  gemm_xwt<<<dim3(8, 8), 256, 0, stream>>>(jx, jw, jb, hidden,
                                           512, 512, 640, 512, 1);
  out_k<<<512, 64, 0, stream>>>(hidden, ow, ob, outp);
}

// Round 7
// 37708.160 us; speedup vs baseline: 5.6218x; 5.6218x over previous
//
#include <hip/hip_runtime.h>
#include <hip/hip_bf16.h>
#include <hip/hip_fp16.h>

// ---------------------------------------------------------------------------
// LuxrNet: conv->conv->FFN (parallel branch) + 2-layer GRU over a 32768-step
// flattened scan (serial branch) + joiner + output head.
// Round 7: fused 2-layer scan, repaired:
//  - ONE merged weight register set (96 h2) shared by the L0/L1 branches
//    (union-live doubling in R6 forced a spill to scratch: VGPR 84 + ~100
//    spilled = the 14x regression). __launch_bounds__(768,3) caps correctly.
//  - LDS h buffers padded to 72-f16 segments so the 4 concurrent read
//    streams hit disjoint banks (R6: 8.4M bank-conflict cycles).
//  - LDS writes gated to one lane per value.
// ---------------------------------------------------------------------------

typedef _Float16 h2_t __attribute__((ext_vector_type(2)));

#if defined(__has_builtin)
#if __has_builtin(__builtin_amdgcn_fdot2)
#define HAVE_FDOT2 1
#endif
#endif

__device__ __forceinline__ h2_t f2h2bits(float x) {
  union { float f; h2_t h; } u; u.f = x; return u.h;
}

__device__ __forceinline__ float fdot2(h2_t a, h2_t b, float c) {
#ifdef HAVE_FDOT2
  return __builtin_amdgcn_fdot2(a, b, c, false);
#else
  return c + (float)a.x * (float)b.x + (float)a.y * (float)b.y;
#endif
}

__device__ __forceinline__ float sigmoidf_(float x) {
  return 1.f / (1.f + __expf(-x));
}
__device__ __forceinline__ float tanhf_(float x) {
  return 2.f / (1.f + __expf(-2.f * x)) - 1.f;
}

// ---------------------------------------------------------------------------
// conv1: in (512,10,30,30), w (64,10,8,8), stride 2 -> out (512,64,12,12), relu
// ---------------------------------------------------------------------------
__global__ __launch_bounds__(256) void conv1_k(
    const float* __restrict__ in, const float* __restrict__ w,
    const float* __restrict__ bias, float* __restrict__ out) {
  int idx = blockIdx.x * 256 + threadIdx.x;     // 512*64*144 total, exact
  int pos = idx % 144;
  int co  = (idx / 144) & 63;
  int b   = idx / (144 * 64);
  int oh = pos / 12, ow = pos % 12;
  const float* ip = in + (size_t)b * 9000 + (oh * 2) * 30 + ow * 2;
  const float* wp = w + co * 640;
  float acc = bias[co];
  for (int ci = 0; ci < 10; ci++) {
#pragma unroll
    for (int kh = 0; kh < 8; kh++) {
      const float* r  = ip + ci * 900 + kh * 30;
      const float* wr = wp + ci * 64 + kh * 8;
#pragma unroll
      for (int kw = 0; kw < 8; kw++) acc += r[kw] * wr[kw];
    }
  }
  out[idx] = fmaxf(acc, 0.f);
}

// ---------------------------------------------------------------------------
// conv2: in (512,64,12,12), w (128,64,4,4), stride 2 -> out (512,128,5,5), relu
// ---------------------------------------------------------------------------
__global__ __launch_bounds__(256) void conv2_k(
    const float* __restrict__ in, const float* __restrict__ w,
    const float* __restrict__ bias, float* __restrict__ out) {
  int idx = blockIdx.x * 256 + threadIdx.x;     // 512*128*25 total, exact
  int pos = idx % 25;
  int co  = (idx / 25) & 127;
  int b   = idx / 3200;
  int oh = pos / 5, ow = pos % 5;
  const float* ip = in + (size_t)b * 9216 + (oh * 2) * 12 + ow * 2;
  const float* wp = w + co * 1024;
  float acc = bias[co];
  for (int ci = 0; ci < 64; ci++) {
#pragma unroll
    for (int kh = 0; kh < 4; kh++) {
      const float* r  = ip + ci * 144 + kh * 12;
      const float* wr = wp + ci * 16 + kh * 4;
#pragma unroll
      for (int kw = 0; kw < 4; kw++) acc += r[kw] * wr[kw];
    }
  }
  out[idx] = fmaxf(acc, 0.f);
}

// ---------------------------------------------------------------------------
// Generic fp32 GEMM: C[m*ldc+n] = bias[n] + sum_k X[m*K+k] * W[n*K+k]
// Requires M%64==0, N%64==0, K%16==0. 64x64 tile, 256 threads, 4x4 micro.
// ---------------------------------------------------------------------------
__global__ __launch_bounds__(256) void gemm_xwt(
    const float* __restrict__ X, const float* __restrict__ W,
    const float* __restrict__ bias, float* __restrict__ C,
    int M, int N, int K, int ldc, int relu) {
  __shared__ float Xs[16][68];
  __shared__ float Ws[16][68];
  int tid = threadIdx.x;
  int m0 = blockIdx.y * 64, n0 = blockIdx.x * 64;
  int lr = tid >> 2;            // 0..63
  int lc = (tid & 3) << 2;      // 0,4,8,12
  int tm = tid >> 4, tn = tid & 15;
  float acc[4][4] = {};
  for (int k0 = 0; k0 < K; k0 += 16) {
    const float4 xv = *(const float4*)(X + (size_t)(m0 + lr) * K + k0 + lc);
    const float4 wv = *(const float4*)(W + (size_t)(n0 + lr) * K + k0 + lc);
    Xs[lc + 0][lr] = xv.x; Xs[lc + 1][lr] = xv.y;
    Xs[lc + 2][lr] = xv.z; Xs[lc + 3][lr] = xv.w;
    Ws[lc + 0][lr] = wv.x; Ws[lc + 1][lr] = wv.y;
    Ws[lc + 2][lr] = wv.z; Ws[lc + 3][lr] = wv.w;
    __syncthreads();
#pragma unroll
    for (int kk = 0; kk < 16; kk++) {
      float a[4], bb[4];
#pragma unroll
      for (int i = 0; i < 4; i++) a[i] = Xs[kk][tm * 4 + i];
#pragma unroll
      for (int j = 0; j < 4; j++) bb[j] = Ws[kk][tn * 4 + j];
#pragma unroll
      for (int i = 0; i < 4; i++)
#pragma unroll
        for (int j = 0; j < 4; j++) acc[i][j] += a[i] * bb[j];
    }
    __syncthreads();
  }
#pragma unroll
  for (int i = 0; i < 4; i++) {
    int m = m0 + tm * 4 + i;
#pragma unroll
    for (int j = 0; j < 4; j++) {
      int n = n0 + tn * 4 + j;
      float v = acc[i][j] + bias[n];
      if (relu) v = fmaxf(v, 0.f);
      C[(size_t)m * ldc + n] = v;
    }
  }
}

// ---------------------------------------------------------------------------
// gi0 = seq @ wih0^T + bih0 where seq[s] = uf[s&511, s>>9, :]  (K=8).
// ---------------------------------------------------------------------------
__global__ __launch_bounds__(384) void gi0_k(
    const float* __restrict__ uf,   // (512,64,8)
    const float* __restrict__ wih,  // (384,8)
    const float* __restrict__ bih,  // (384)
    float* __restrict__ gi) {       // (32768,384)
  int n = threadIdx.x;
  int s0 = blockIdx.x * 32;
  __shared__ float xs[32][8];
  if (n < 256) {
    int ss = s0 + (n >> 3);
    int k = n & 7;
    xs[n >> 3][k] = uf[(size_t)(ss & 511) * 512 + (ss >> 9) * 8 + k];
  }
  float w[8];
#pragma unroll
  for (int k = 0; k < 8; k++) w[k] = wih[n * 8 + k];
  float b = bih[n];
  __syncthreads();
#pragma unroll 4
  for (int i = 0; i < 32; i++) {
    float a = b;
#pragma unroll
    for (int k = 0; k < 8; k++) a += w[k] * xs[i][k];
    gi[(size_t)(s0 + i) * 384 + n] = a;
  }
}

// ---------------------------------------------------------------------------
// Fused 2-layer GRU scan. One WG, 768 threads (12 waves), pipelined:
// at slot s, L0 (t<256, pair-split K=128) computes h1[s]; L1 (t>=256,
// quad-split over concat K=256 [wih1*h1 | whh1*h2]) computes h2[s-1].
// ONE weight register set (w0/w1/w2: 96 h2) shared by both branches.
// h state in padded LDS segments hseg[8][72] (64 f16 + 8 pad): concurrent
// read streams start at banks {0,4,16,20}/{8,12,24,28} -> conflict-free.
// One barrier per slot (lgkmcnt-only; gi prefetch loads stay in flight).
// ---------------------------------------------------------------------------
#define L0_STEP(SIN, SOUT, G0, G1, G2)                                        \
  {                                                                           \
    const float4* hp4 = (const float4*)(hseg[(SIN) + half]);                  \
    float ar = b0, az = b1, an = b2;                                          \
    _Pragma("unroll")                                                         \
    for (int q = 0; q < 8; q++) {                                             \
      float4 blk = hp4[q];                                                    \
      h2_t x0 = f2h2bits(blk.x), x1 = f2h2bits(blk.y);                        \
      h2_t x2 = f2h2bits(blk.z), x3 = f2h2bits(blk.w);                        \
      ar = fdot2(w0[4*q+0], x0, ar); az = fdot2(w1[4*q+0], x0, az);           \
      an = fdot2(w2[4*q+0], x0, an);                                          \
      ar = fdot2(w0[4*q+1], x1, ar); az = fdot2(w1[4*q+1], x1, az);           \
      an = fdot2(w2[4*q+1], x1, an);                                          \
      ar = fdot2(w0[4*q+2], x2, ar); az = fdot2(w1[4*q+2], x2, az);           \
      an = fdot2(w2[4*q+2], x2, an);                                          \
      ar = fdot2(w0[4*q+3], x3, ar); az = fdot2(w1[4*q+3], x3, az);           \
      an = fdot2(w2[4*q+3], x3, an);                                          \
    }                                                                         \
    ar += __shfl_xor(ar, 1); az += __shfl_xor(az, 1); an += __shfl_xor(an, 1);\
    float r = sigmoidf_((G0) + ar);                                           \
    float z = sigmoidf_((G1) + az);                                           \
    float n = tanhf_((G2) + r * an);                                          \
    float hn = (1.f - z) * n + z * hreg;                                      \
    hreg = hn;                                                                \
    if (half == 0) hseg[(SOUT) + (o >> 6)][o & 63] = (_Float16)hn;            \
  }

#define L1_STEP(S1R, S2R, S2W, SIDX)                                          \
  {                                                                           \
    const float4* xp4 =                                                       \
        (const float4*)(hseg[((c < 2) ? (S1R) : (S2R)) + (c & 1)]);           \
    float ar = b0, az = b1, an = b2;                                          \
    _Pragma("unroll")                                                         \
    for (int q = 0; q < 8; q++) {                                             \
      float4 blk = xp4[q];                                                    \
      h2_t x0 = f2h2bits(blk.x), x1 = f2h2bits(blk.y);                        \
      h2_t x2 = f2h2bits(blk.z), x3 = f2h2bits(blk.w);                        \
      ar = fdot2(w0[4*q+0], x0, ar); az = fdot2(w1[4*q+0], x0, az);           \
      an = fdot2(w2[4*q+0], x0, an);                                          \
      ar = fdot2(w0[4*q+1], x1, ar); az = fdot2(w1[4*q+1], x1, az);           \
      an = fdot2(w2[4*q+1], x1, an);                                          \
      ar = fdot2(w0[4*q+2], x2, ar); az = fdot2(w1[4*q+2], x2, az);           \
      an = fdot2(w2[4*q+2], x2, an);                                          \
      ar = fdot2(w0[4*q+3], x3, ar); az = fdot2(w1[4*q+3], x3, az);           \
      an = fdot2(w2[4*q+3], x3, an);                                          \
    }                                                                         \
    ar += __shfl_xor(ar, 1); az += __shfl_xor(az, 1); an += __shfl_xor(an, 1);\
    float or_ = __shfl_xor(ar, 2), oz = __shfl_xor(az, 2),                    \
          on = __shfl_xor(an, 2);                                             \
    float pre_r = ar + or_, pre_z = az + oz;                                  \
    float i_n = (c < 2) ? an : on;                                            \
    float h_n = (c < 2) ? on : an;                                            \
    float r = sigmoidf_(pre_r);                                               \
    float z = sigmoidf_(pre_z);                                               \
    float n = tanhf_(i_n + r * h_n);                                          \
    float hn = (1.f - z) * n + z * hreg;                                      \
    hreg = hn;                                                                \
    if (c == 0) {                                                             \
      hseg[(S2W) + (o1 >> 6)][o1 & 63] = (_Float16)hn;                        \
      if ((SIDX) >= S - 511)                                                  \
        jx[(size_t)((SIDX) - 1 - (S - 512)) * 640 + 512 + o1] = hn;           \
    }                                                                         \
  }

#define GRU_RELOAD(G0, G1, G2)                                                \
  { G0 = gp[0]; G1 = gp[128]; G2 = gp[256]; gp += 384; }

#define GRU_BARRIER()                                                         \
  __builtin_amdgcn_sched_barrier(0);                                          \
  asm volatile("s_waitcnt lgkmcnt(0)" ::: "memory");                          \
  __builtin_amdgcn_s_barrier();                                               \
  __builtin_amdgcn_sched_barrier(0);

// segment indices: h1a=0(+1), h1b=2(+1), h2a=4(+1), h2b=6(+1)
#define FUSED_SLOT(S1R, S1W, S2R, S2W, G0, G1, G2, SIDX)                      \
  if (isL0) {                                                                 \
    if ((SIDX) < S) { L0_STEP(S1R, S1W, G0, G1, G2); }                        \
    GRU_RELOAD(G0, G1, G2);                                                   \
  } else {                                                                    \
    if ((SIDX) >= 1 && (SIDX) <= S) { L1_STEP(S1R, S2R, S2W, SIDX); }         \
  }                                                                           \
  GRU_BARRIER();

__global__ __launch_bounds__(768, 3) void fused_scan(
    const float* __restrict__ gi0,   // (S,384), includes bih0
    const float* __restrict__ whh0,  // (384,128)
    const float* __restrict__ bhh0,  // (384)
    const float* __restrict__ wih1,  // (384,128)
    const float* __restrict__ whh1,  // (384,128)
    const float* __restrict__ bih1,  // (384)
    const float* __restrict__ bhh1,  // (384)
    float* __restrict__ jx) {        // (512,640), cols 512..639
  const int S = 32768;
  const int t = threadIdx.x;
  const bool isL0 = (t < 256);

  // 8 segments of 64 f16 + 8 pad: bank-disjoint concurrent read streams.
  alignas(16) __shared__ _Float16 hseg[8][72];

  const int o = (t < 256) ? (t >> 1) : 0;   // L0 output index
  const int half = t & 1;                   // L0 K-half
  const int u = t - 256;
  const int o1 = (t >= 256) ? (u >> 2) : 0; // L1 output index
  const int c = u & 3;                      // L1 K-quarter

  // ONE register weight set for both branches (96 h2 = 96 VGPRs).
  h2_t w0[32], w1[32], w2[32];
  float b0 = 0.f, b1 = 0.f, b2 = 0.f;
  float hreg = 0.f;

  if (isL0) {
    const float2* pr = (const float2*)(whh0 + (size_t)(o)       * 128 + half * 64);
    const float2* pz = (const float2*)(whh0 + (size_t)(128 + o) * 128 + half * 64);
    const float2* pn = (const float2*)(whh0 + (size_t)(256 + o) * 128 + half * 64);
#pragma unroll
    for (int k = 0; k < 32; k++) {
      float2 a = pr[k], b = pz[k], d = pn[k];
      h2_t va; va.x = (_Float16)a.x; va.y = (_Float16)a.y; w0[k] = va;
      h2_t vb; vb.x = (_Float16)b.x; vb.y = (_Float16)b.y; w1[k] = vb;
      h2_t vc; vc.x = (_Float16)d.x; vc.y = (_Float16)d.y; w2[k] = vc;
    }
    if (half == 0) { b0 = bhh0[o]; b1 = bhh0[128 + o]; b2 = bhh0[256 + o]; }
  } else {
    // lanes c=0,1: wih1 halves (i_*); lanes c=2,3: whh1 halves (h_*)
    const float* M = (c < 2) ? wih1 : whh1;
    const float2* pr = (const float2*)(M + (size_t)(o1)       * 128 + (c & 1) * 64);
    const float2* pz = (const float2*)(M + (size_t)(128 + o1) * 128 + (c & 1) * 64);
    const float2* pn = (const float2*)(M + (size_t)(256 + o1) * 128 + (c & 1) * 64);
#pragma unroll
    for (int k = 0; k < 32; k++) {
      float2 a = pr[k], b = pz[k], d = pn[k];
      h2_t va; va.x = (_Float16)a.x; va.y = (_Float16)a.y; w0[k] = va;
      h2_t vb; vb.x = (_Float16)b.x; vb.y = (_Float16)b.y; w1[k] = vb;
      h2_t vc; vc.x = (_Float16)d.x; vc.y = (_Float16)d.y; w2[k] = vc;
    }
    if (c == 0) { b0 = bih1[o1]; b1 = bih1[128 + o1]; b2 = bih1[256 + o1]; }
    if (c == 2) { b0 = bhh1[o1]; b1 = bhh1[128 + o1]; b2 = bhh1[256 + o1]; }
  }

  if (t < 576) ((_Float16*)hseg)[t] = (_Float16)0.f;  // zero all segs + pads

  // depth-4 register prefetch of gi0 rows (L0 threads only)
  const float* gp = gi0 + o;
  float gA0 = 0, gA1 = 0, gA2 = 0, gB0 = 0, gB1 = 0, gB2 = 0;
  float gC0 = 0, gC1 = 0, gC2 = 0, gD0 = 0, gD1 = 0, gD2 = 0;
  if (isL0) {
    GRU_RELOAD(gA0, gA1, gA2);
    GRU_RELOAD(gB0, gB1, gB2);
    GRU_RELOAD(gC0, gC1, gC2);
    GRU_RELOAD(gD0, gD1, gD2);
  }
  __syncthreads();

  // 32772 slots (last 3 are L0 no-ops); L0 active s<S, L1 active 1<=s<=S.
  // Tail prefetch reads gi0 rows 32768..32775 -> land in jx region of d_ws
  // (in-bounds, barrier-ordered after jx tail writes, values unused).
  for (int s = 0; s < 32772; s += 4) {
    FUSED_SLOT(0, 2, 4, 6, gA0, gA1, gA2, s);
    FUSED_SLOT(2, 0, 6, 4, gB0, gB1, gB2, s + 1);
    FUSED_SLOT(0, 2, 4, 6, gC0, gC1, gC2, s + 2);
    FUSED_SLOT(2, 0, 6, 4, gD0, gD1, gD2, s + 3);
  }
}

// ---------------------------------------------------------------------------
// out head: out[b,:] = hidden[b,:] @ out_w.T + out_b (relu pre-applied)
// ---------------------------------------------------------------------------
__global__ __launch_bounds__(64) void out_k(
    const float* __restrict__ hidden, const float* __restrict__ ow,
    const float* __restrict__ ob, float* __restrict__ out) {
  __shared__ float hrow[512];
  int b = blockIdx.x, t = threadIdx.x;
  float4* h4 = (float4*)hrow;
  const float4* src = (const float4*)(hidden + (size_t)b * 512);
  h4[t] = src[t];
  h4[t + 64] = src[t + 64];
  __syncthreads();
  if (t < 12) {
    float acc = ob[t];
    const float* wr = ow + t * 512;
    for (int k = 0; k < 512; k++) acc += hrow[k] * wr[k];
    out[(size_t)b * 12 + t] = acc;
  }
}

// ---------------------------------------------------------------------------
extern "C" void kernel_launch(void* const* d_in, const int* in_sizes, int n_in,
                              void* d_out, int out_size, void* d_ws,
                              size_t ws_size, hipStream_t stream) {
  const float* gf    = (const float*)d_in[0];   // (512,10,30,30)
  const float* uf    = (const float*)d_in[1];   // (512,64,8)
  const float* c1w   = (const float*)d_in[2];
  const float* c1b   = (const float*)d_in[3];
  const float* c2w   = (const float*)d_in[4];
  const float* c2b   = (const float*)d_in[5];
  const float* ffw   = (const float*)d_in[6];
  const float* ffb   = (const float*)d_in[7];
  const float* wih0  = (const float*)d_in[8];
  const float* whh0  = (const float*)d_in[9];
  const float* bih0  = (const float*)d_in[10];
  const float* bhh0  = (const float*)d_in[11];
  const float* wih1  = (const float*)d_in[12];
  const float* whh1  = (const float*)d_in[13];
  const float* bih1  = (const float*)d_in[14];
  const float* bhh1  = (const float*)d_in[15];
  const float* jw    = (const float*)d_in[16];
  const float* jb    = (const float*)d_in[17];
  const float* ow    = (const float*)d_in[18];
  const float* ob    = (const float*)d_in[19];
  float* outp = (float*)d_out;                  // (512,12)

  // workspace layout (floats). gi time-shares with conv scratch (conv1o/
  // conv2o dead before gi0 is written).
  float* ws     = (float*)d_ws;
  float* gi     = ws;                 // 32768*384 = 12,582,912 f
  float* conv1o = ws;                 //  4,718,592 f (aliases gi, earlier)
  float* conv2o = ws + 4718592;       //  1,638,400 f (aliases gi, earlier)
  float* jx     = ws + 12582912;      //  512*640 = 327,680 f
  float* hidden = jx + 327680;        //  512*512 = 262,144 f
  // total: ~13.17M floats = ~52.7 MB

  conv1_k<<<18432, 256, 0, stream>>>(gf, c1w, c1b, conv1o);
  conv2_k<<<6400, 256, 0, stream>>>(conv1o, c2w, c2b, conv2o);
  // glob = conv2o(512,3200) @ ffw.T + ffb -> jx cols [0,512)
  gemm_xwt<<<dim3(8, 8), 256, 0, stream>>>(conv2o, ffw, ffb, jx,
                                           512, 512, 3200, 640, 0);
  // gi0 = seq @ wih0^T + bih0  (overwrites conv scratch, now dead)
  gi0_k<<<1024, 384, 0, stream>>>(uf, wih0, bih0, gi);
  // fused 2-layer GRU scan; writes last 512 h2 rows into jx cols [512,640)
  fused_scan<<<1, 768, 0, stream>>>(gi, whh0, bhh0, wih1, whh1, bih1, bhh1,
                                    jx);
  // hidden = relu(jx(512,640) @ jw.T + jb)
  gemm_xwt<<<dim3(8, 8), 256, 0, stream>>>(jx, jw, jb, hidden,
                                           512, 512, 640, 512, 1);
  out_k<<<512, 64, 0, stream>>>(hidden, ow, ob, outp);
}